// Round 8
// baseline (232.716 us; speedup 1.0000x reference)
//
#include <hip/hip_runtime.h>
#include <stdint.h>

#define KSTEPS 24              // 768 / 32
#define TOKENS 16384           // B*S

typedef short short8 __attribute__((ext_vector_type(8)));
typedef float fx4 __attribute__((ext_vector_type(4)));
typedef unsigned short u16;
typedef u16 u16x4 __attribute__((ext_vector_type(4)));

static __device__ __forceinline__ u16 f2bf(float f) {
  union { float f; unsigned u; } v; v.f = f;
  return (u16)((v.u + 0x7fffu + ((v.u >> 16) & 1u)) >> 16);
}

static __device__ __forceinline__ fx4 mfma16(short8 a, short8 b, fx4 c) {
  return __builtin_amdgcn_mfma_f32_16x16x32_bf16(a, b, c, 0, 0, 0);
}

// ---------------- prep: W[768][64] fp32 (q,k,v) -> bf16 pre-fragmented B-operand layout
__global__ void prep_w_kernel(const float* __restrict__ Wq, const float* __restrict__ Wk,
                              const float* __restrict__ Wv, u16* __restrict__ wfrag) {
  int idx  = blockIdx.x * 256 + threadIdx.x;   // 72*256 = 18432 = 3*24*4*64
  int lane = idx & 63;
  int fid  = idx >> 6;
  int nt   = fid & 3;
  int ks   = (fid >> 2) % KSTEPS;
  int mat  = fid / (KSTEPS * 4);
  const float* W = (mat == 0) ? Wq : (mat == 1) ? Wk : Wv;
  int n  = nt * 16 + (lane & 15);
  int k0 = ks * 32 + (lane >> 4) * 8;
  short8 out;
#pragma unroll
  for (int j = 0; j < 8; j++) out[j] = (short)f2bf(W[(size_t)(k0 + j) * 64 + n]);
  *(short8*)(wfrag + (size_t)idx * 8) = out;
}

// ---------------- projection GEMM v3 (unchanged this round: control variable)
// 16 tok/block, 1024 blocks, 4 waves = 4 col-splits (3 (m,nt)-tiles each).
// A (x) and B (wfrag) both global->VGPR with depth-2 prefetch. No LDS, no barriers.
__global__ __launch_bounds__(256) void proj_kernel(const float* __restrict__ x,
                                                   const u16* __restrict__ wfrag,
                                                   u16* __restrict__ qb,
                                                   u16* __restrict__ kb,
                                                   u16* __restrict__ vT) {
  int cs = threadIdx.x >> 6, lane = threadIdx.x & 63;
  int ln = lane & 15, quad = lane >> 4;
  int s0 = blockIdx.x * 16;

  const float* xp = x + (size_t)(s0 + ln) * 768 + quad * 8;
  const u16* wb[3];
#pragma unroll
  for (int j = 0; j < 3; j++) {
    int f = cs * 3 + j, m = f >> 2, nt = f & 3;
    wb[j] = wfrag + ((size_t)m * KSTEPS * 256 + nt * 64 + lane) * 8;
  }

  fx4 acc[3];
#pragma unroll
  for (int j = 0; j < 3; j++) acc[j] = (fx4){0.f, 0.f, 0.f, 0.f};

  fx4 xr[2][2];
  short8 wr[2][3];
#pragma unroll
  for (int s = 0; s < 2; s++) {
    xr[s][0] = *(const fx4*)(xp + s * 32);
    xr[s][1] = *(const fx4*)(xp + s * 32 + 4);
#pragma unroll
    for (int j = 0; j < 3; j++) wr[s][j] = *(const short8*)(wb[j] + (size_t)s * 2048);
  }

#pragma unroll 2
  for (int ks = 0; ks < KSTEPS; ks++) {
    int c = ks & 1;
    short8 af;
#pragma unroll
    for (int j = 0; j < 4; j++) {
      af[j]     = (short)f2bf(xr[c][0][j]);
      af[4 + j] = (short)f2bf(xr[c][1][j]);
    }
#pragma unroll
    for (int j = 0; j < 3; j++) acc[j] = mfma16(af, wr[c][j], acc[j]);
    if (ks < KSTEPS - 2) {
      xr[c][0] = *(const fx4*)(xp + (ks + 2) * 32);
      xr[c][1] = *(const fx4*)(xp + (ks + 2) * 32 + 4);
#pragma unroll
      for (int j = 0; j < 3; j++)
        wr[c][j] = *(const short8*)(wb[j] + (size_t)(ks + 2) * 2048);
    }
  }

  int tok0 = s0 + quad * 4;
#pragma unroll
  for (int j = 0; j < 3; j++) {
    int f = cs * 3 + j;
    int d = (f & 3) * 16 + ln;
    if (f < 4) {
#pragma unroll
      for (int reg = 0; reg < 4; reg++)
        qb[(size_t)(tok0 + reg) * 64 + d] = f2bf(acc[j][reg] * 0.180336887f);
    } else if (f < 8) {
#pragma unroll
      for (int reg = 0; reg < 4; reg++)
        kb[(size_t)(tok0 + reg) * 64 + d] = f2bf(acc[j][reg]);
    } else {
      int b = tok0 >> 12, s = tok0 & 4095;
      u16x4 vp;
#pragma unroll
      for (int reg = 0; reg < 4; reg++) vp[reg] = f2bf(acc[j][reg]);
      *(u16x4*)(vT + ((size_t)b * 64 + d) * 4096 + s) = vp;
    }
  }
}

// ---------------- flash attention v4: WAVE-INDEPENDENT, zero barriers.
// Each wave: 16 Q-rows (one band) of one batch, one split-K half. Static-max
// softmax (p = 2^s). K/V frags: plain coalesced b128 global loads (L2-hot).
// Latency hidden by TLP: launch_bounds(256,4) -> VGPR<=128 -> 16 waves/CU.
__global__ __launch_bounds__(256, 4) void attn_kernel(const u16* __restrict__ qb,
                                                      const u16* __restrict__ kb,
                                                      const u16* __restrict__ vT,
                                                      float* __restrict__ o0g,
                                                      float* __restrict__ po1,
                                                      float* __restrict__ mlb) {
  __shared__ u16 Ps[4][16 * 72];      // per-wave P round-trip, padded rows

  int w = threadIdx.x >> 6, lane = threadIdx.x & 63;
  int ln = lane & 15, quad = lane >> 4;
  int band = 255 - blockIdx.x;        // 16-row band, big workloads first
  int z = blockIdx.y;                 // split-K half
  int b = w;                          // wave = batch -> identical work per wave
  int q0 = band * 16;

  const u16* qbb = qb + (size_t)b * 4096 * 64;
  const u16* kbb = kb + (size_t)b * 4096 * 64;
  const u16* vtb = vT + (size_t)b * 64 * 4096;

  short8 qf0 = *(const short8*)(qbb + (size_t)(q0 + ln) * 64 + quad * 8);
  short8 qf1 = *(const short8*)(qbb + (size_t)(q0 + ln) * 64 + 32 + quad * 8);

  short8 ones;
#pragma unroll
  for (int j = 0; j < 8; j++) ones[j] = (short)0x3F80;   // bf16 1.0

  fx4 o[4];
#pragma unroll
  for (int nt2 = 0; nt2 < 4; nt2++) o[nt2] = (fx4){0.f, 0.f, 0.f, 0.f};
  float l_i[4] = {0.f, 0.f, 0.f, 0.f};

  int n = (q0 + 79) >> 6;             // 64-key tiles this band needs
  int h = (n + 1) >> 1;
  int lo = z ? h : 0, hi = z ? n : h;

  // B-frag bases: K: lane ln -> key, quad -> d-chunk (16B contig in kb[tok][64])
  //               V: lane ln -> d, quad -> key-chunk (16B contig in vT[d][4096])
  const u16* kfp = kbb + (size_t)ln * 64 + quad * 8;
  const u16* vfp = vtb + (size_t)ln * 4096 + quad * 8;

  for (int t = lo; t < hi; t++) {
    // issue all 16 loads up front; QK waits on kf, vf lands during softmax
    short8 kf[8], vf[8];
#pragma unroll
    for (int nt = 0; nt < 4; nt++) {
      kf[nt * 2]     = *(const short8*)(kfp + (size_t)(t * 64 + nt * 16) * 64);
      kf[nt * 2 + 1] = *(const short8*)(kfp + (size_t)(t * 64 + nt * 16) * 64 + 32);
      vf[nt * 2]     = *(const short8*)(vfp + (size_t)(nt * 16) * 4096 + t * 64);
      vf[nt * 2 + 1] = *(const short8*)(vfp + (size_t)(nt * 16) * 4096 + t * 64 + 32);
    }

    fx4 sA[4];
#pragma unroll
    for (int nt = 0; nt < 4; nt++) {
      sA[nt] = mfma16(qf0, kf[nt * 2], (fx4){0.f, 0.f, 0.f, 0.f});
      sA[nt] = mfma16(qf1, kf[nt * 2 + 1], sA[nt]);
    }

    if (t == n - 1) {  // diagonal tile mask
#pragma unroll
      for (int nt = 0; nt < 4; nt++)
#pragma unroll
        for (int reg = 0; reg < 4; reg++) {
          int col = t * 64 + nt * 16 + ln;
          int rowg = q0 + quad * 4 + reg;
          if (col > rowg) sA[nt][reg] = -1e30f;
        }
    }

    // static max: p = 2^s (normalizer cancels); C-layout -> A-layout via LDS
#pragma unroll
    for (int nt = 0; nt < 4; nt++)
#pragma unroll
      for (int reg = 0; reg < 4; reg++)
        Ps[w][(quad * 4 + reg) * 72 + nt * 16 + ln] =
            f2bf(__builtin_amdgcn_exp2f(sA[nt][reg]));

    short8 pf0 = *(const short8*)(&Ps[w][ln * 72 + quad * 8]);
    short8 pf1 = *(const short8*)(&Ps[w][ln * 72 + 32 + quad * 8]);

    // row-sum of P via MFMA with ones-B
    fx4 lacc = mfma16(pf0, ones, (fx4){0.f, 0.f, 0.f, 0.f});
    lacc = mfma16(pf1, ones, lacc);
#pragma unroll
    for (int reg = 0; reg < 4; reg++) l_i[reg] += lacc[reg];

#pragma unroll
    for (int nt2 = 0; nt2 < 4; nt2++) {
      o[nt2] = mfma16(pf0, vf[nt2 * 2], o[nt2]);
      o[nt2] = mfma16(pf1, vf[nt2 * 2 + 1], o[nt2]);
    }
  }

  // write unnormalized partial + l (no merges needed inside the block)
  float* dst = z ? po1 : o0g;
#pragma unroll
  for (int nt2 = 0; nt2 < 4; nt2++)
#pragma unroll
    for (int reg = 0; reg < 4; reg++) {
      int rowg = q0 + quad * 4 + reg;
      dst[((size_t)b * 4096 + rowg) * 64 + nt2 * 16 + ln] = o[nt2][reg];
    }
  if (ln == 0) {
#pragma unroll
    for (int reg = 0; reg < 4; reg++) {
      int rowg = q0 + quad * 4 + reg;
      mlb[((size_t)z * 4 + b) * 4096 + rowg] = l_i[reg];
    }
  }
}

// ---------------- merge the two split-K halves: out = (o0 + o1) / (l0 + l1)
__global__ __launch_bounds__(256) void merge_kernel(float* __restrict__ out,
                                                    const float* __restrict__ po1,
                                                    const float* __restrict__ mlb) {
  int qt = blockIdx.x, b = blockIdx.y;
  int r = threadIdx.x >> 3;
  int c = (threadIdx.x & 7) * 8;
  size_t row = (size_t)b * 4096 + qt * 32 + r;
  float l = mlb[row] + mlb[(size_t)4 * 4096 + row];
  float inv = 1.0f / l;
  float* op = out + row * 64 + c;
  const float* p1p = po1 + row * 64 + c;
  fx4 u0 = *(fx4*)op, u1 = *(fx4*)(op + 4);
  fx4 v0 = *(const fx4*)p1p, v1 = *(const fx4*)(p1p + 4);
#pragma unroll
  for (int j = 0; j < 4; j++) {
    u0[j] = (u0[j] + v0[j]) * inv;
    u1[j] = (u1[j] + v1[j]) * inv;
  }
  *(fx4*)op = u0;
  *(fx4*)(op + 4) = u1;
}

extern "C" void kernel_launch(void* const* d_in, const int* in_sizes, int n_in,
                              void* d_out, int out_size, void* d_ws, size_t ws_size,
                              hipStream_t stream) {
  const float* x  = (const float*)d_in[0];
  const float* Wq = (const float*)d_in[1];
  const float* Wk = (const float*)d_in[2];
  const float* Wv = (const float*)d_in[3];

  u16* qbw = (u16*)d_ws;                          // [16384][64] bf16, 2MB
  u16* kbw = qbw + (size_t)TOKENS * 64;           // 2MB
  u16* vtw = kbw + (size_t)TOKENS * 64;           // 2MB
  u16* wfr = vtw + (size_t)TOKENS * 64;           // 288KB
  float* po1 = (float*)(wfr + (size_t)3 * KSTEPS * 256 * 8);  // [4][4096][64] fp32, 4MB
  float* mlb = po1 + (size_t)4 * 4096 * 64;       // [2][4][4096] float, 128KB

  prep_w_kernel<<<72, 256, 0, stream>>>(Wq, Wk, Wv, wfr);
  proj_kernel<<<TOKENS / 16, 256, 0, stream>>>(x, wfr, qbw, kbw, vtw);
  attn_kernel<<<dim3(256, 2), 256, 0, stream>>>(qbw, kbw, vtw,
                                                (float*)d_out, po1, mlb);
  merge_kernel<<<dim3(128, 4), 256, 0, stream>>>((float*)d_out, po1, mlb);
}

// Round 9
// 185.321 us; speedup vs baseline: 1.2557x; 1.2557x over previous
//
#include <hip/hip_runtime.h>
#include <stdint.h>

#define KSTEPS 24              // 768 / 32
#define TOKENS 16384           // B*S

typedef short short8 __attribute__((ext_vector_type(8)));
typedef float fx4 __attribute__((ext_vector_type(4)));
typedef unsigned short u16;
typedef u16 u16x4 __attribute__((ext_vector_type(4)));

static __device__ __forceinline__ u16 f2bf(float f) {
  union { float f; unsigned u; } v; v.f = f;
  return (u16)((v.u + 0x7fffu + ((v.u >> 16) & 1u)) >> 16);
}

static __device__ __forceinline__ fx4 mfma16(short8 a, short8 b, fx4 c) {
  return __builtin_amdgcn_mfma_f32_16x16x32_bf16(a, b, c, 0, 0, 0);
}

// async global->LDS, 16B/lane; lds dest = wave-uniform base + lane*16
static __device__ __forceinline__ void async16(const void* g, void* l) {
  __builtin_amdgcn_global_load_lds(
      (const __attribute__((address_space(1))) void*)g,
      (__attribute__((address_space(3))) void*)(unsigned int)(uintptr_t)l,
      16, 0, 0);
}

// ---------------- prep: W[768][64] fp32 (q,k,v) -> bf16 pre-fragmented B-operand layout
__global__ void prep_w_kernel(const float* __restrict__ Wq, const float* __restrict__ Wk,
                              const float* __restrict__ Wv, u16* __restrict__ wfrag) {
  int idx  = blockIdx.x * 256 + threadIdx.x;   // 72*256 = 18432 = 3*24*4*64
  int lane = idx & 63;
  int fid  = idx >> 6;
  int nt   = fid & 3;
  int ks   = (fid >> 2) % KSTEPS;
  int mat  = fid / (KSTEPS * 4);
  const float* W = (mat == 0) ? Wq : (mat == 1) ? Wk : Wv;
  int n  = nt * 16 + (lane & 15);
  int k0 = ks * 32 + (lane >> 4) * 8;
  short8 out;
#pragma unroll
  for (int j = 0; j < 8; j++) out[j] = (short)f2bf(W[(size_t)(k0 + j) * 64 + n]);
  *(short8*)(wfrag + (size_t)idx * 8) = out;
}

// ---------------- projection GEMM v3 (unchanged: control variable this round)
__global__ __launch_bounds__(256) void proj_kernel(const float* __restrict__ x,
                                                   const u16* __restrict__ wfrag,
                                                   u16* __restrict__ qb,
                                                   u16* __restrict__ kb,
                                                   u16* __restrict__ vT) {
  int cs = threadIdx.x >> 6, lane = threadIdx.x & 63;
  int ln = lane & 15, quad = lane >> 4;
  int s0 = blockIdx.x * 16;

  const float* xp = x + (size_t)(s0 + ln) * 768 + quad * 8;
  const u16* wb[3];
#pragma unroll
  for (int j = 0; j < 3; j++) {
    int f = cs * 3 + j, m = f >> 2, nt = f & 3;
    wb[j] = wfrag + ((size_t)m * KSTEPS * 256 + nt * 64 + lane) * 8;
  }

  fx4 acc[3];
#pragma unroll
  for (int j = 0; j < 3; j++) acc[j] = (fx4){0.f, 0.f, 0.f, 0.f};

  fx4 xr[2][2];
  short8 wr[2][3];
#pragma unroll
  for (int s = 0; s < 2; s++) {
    xr[s][0] = *(const fx4*)(xp + s * 32);
    xr[s][1] = *(const fx4*)(xp + s * 32 + 4);
#pragma unroll
    for (int j = 0; j < 3; j++) wr[s][j] = *(const short8*)(wb[j] + (size_t)s * 2048);
  }

#pragma unroll 2
  for (int ks = 0; ks < KSTEPS; ks++) {
    int c = ks & 1;
    short8 af;
#pragma unroll
    for (int j = 0; j < 4; j++) {
      af[j]     = (short)f2bf(xr[c][0][j]);
      af[4 + j] = (short)f2bf(xr[c][1][j]);
    }
#pragma unroll
    for (int j = 0; j < 3; j++) acc[j] = mfma16(af, wr[c][j], acc[j]);
    if (ks < KSTEPS - 2) {
      xr[c][0] = *(const fx4*)(xp + (ks + 2) * 32);
      xr[c][1] = *(const fx4*)(xp + (ks + 2) * 32 + 4);
#pragma unroll
      for (int j = 0; j < 3; j++)
        wr[c][j] = *(const short8*)(wb[j] + (size_t)(ks + 2) * 2048);
    }
  }

  int tok0 = s0 + quad * 4;
#pragma unroll
  for (int j = 0; j < 3; j++) {
    int f = cs * 3 + j;
    int d = (f & 3) * 16 + ln;
    if (f < 4) {
#pragma unroll
      for (int reg = 0; reg < 4; reg++)
        qb[(size_t)(tok0 + reg) * 64 + d] = f2bf(acc[j][reg] * 0.180336887f);
    } else if (f < 8) {
#pragma unroll
      for (int reg = 0; reg < 4; reg++)
        kb[(size_t)(tok0 + reg) * 64 + d] = f2bf(acc[j][reg]);
    } else {
      int b = tok0 >> 12, s = tok0 & 4095;
      u16x4 vp;
#pragma unroll
      for (int reg = 0; reg < 4; reg++) vp[reg] = f2bf(acc[j][reg]);
      *(u16x4*)(vT + ((size_t)b * 64 + d) * 4096 + s) = vp;
    }
  }
}

// ---------------- flash attention v5: BM=64, 4 row-waves share one staged K tile.
// Split-K 4-way across blocks; static-max softmax (p = 2^s, partials additive);
// K via global_load_lds dbuf (8KB/round for 64 Q-rows), V direct-to-reg.
__global__ __launch_bounds__(256) void attn_kernel(const u16* __restrict__ qb,
                                                   const u16* __restrict__ kb,
                                                   const u16* __restrict__ vT,
                                                   float* __restrict__ o0g,
                                                   float* __restrict__ po123,
                                                   float* __restrict__ mlb) {
  __shared__ u16 Kstg[2][4096];       // [buf][64 keys * 64 d] = 16KB
  __shared__ u16 Ps[4][16 * 72];      // per-wave P round-trip, padded rows

  int w = threadIdx.x >> 6, lane = threadIdx.x & 63;
  int ln = lane & 15, quad = lane >> 4;
  int band = 63 - blockIdx.x;         // 64-row band, big workloads first
  int b = blockIdx.y, z = blockIdx.z; // batch, split-K quarter
  int q0 = band * 64;

  const u16* qbb = qb + (size_t)b * 4096 * 64;
  const u16* kbb = kb + (size_t)b * 4096 * 64;
  const u16* vtb = vT + (size_t)b * 64 * 4096;

  short8 qf0 = *(const short8*)(qbb + (size_t)(q0 + w * 16 + ln) * 64 + quad * 8);
  short8 qf1 = *(const short8*)(qbb + (size_t)(q0 + w * 16 + ln) * 64 + 32 + quad * 8);

  short8 ones;
#pragma unroll
  for (int j = 0; j < 8; j++) ones[j] = (short)0x3F80;   // bf16 1.0

  fx4 o[4];
#pragma unroll
  for (int nt2 = 0; nt2 < 4; nt2++) o[nt2] = (fx4){0.f, 0.f, 0.f, 0.f};
  float l_i[4] = {0.f, 0.f, 0.f, 0.f};

  int n = band + 1;                   // 64-key tiles this band needs
  int c = (n + 3) >> 2;               // tiles per split-K quarter
  int lo = z * c; if (lo > n) lo = n;
  int hi = lo + c; if (hi > n) hi = n;

  // V B-frag base: lane ln -> d, quad -> key-chunk; 16B contig in vT[d][4096]
  const u16* vfp = vtb + (size_t)ln * 4096 + quad * 8;

  // K staging: 8KB tile = 512 x 16B chunks; 2 chunks/thread, swizzled source
  if (lo < hi) {
#pragma unroll
    for (int j = 0; j < 2; j++) {
      int cc = (w * 2 + j) * 64 + lane;
      int row = cc >> 3, slot = cc & 7;
      async16(kbb + ((size_t)lo * 64 + row) * 64 + (slot ^ (row & 7)) * 8,
              (char*)Kstg[0] + (w * 2 + j) * 1024);
    }
  }

  for (int t = lo; t < hi; t++) {
    __syncthreads();                  // publishes buf (t-lo)&1
    // V frags issued first (consumed at round end -> in-round latency cover)
    short8 vf[8];
#pragma unroll
    for (int nt2 = 0; nt2 < 4; nt2++) {
      vf[nt2 * 2]     = *(const short8*)(vfp + (size_t)(nt2 * 16) * 4096 + t * 64);
      vf[nt2 * 2 + 1] = *(const short8*)(vfp + (size_t)(nt2 * 16) * 4096 + t * 64 + 32);
    }
    if (t + 1 < hi) {                 // prefetch next K tile into other buf
      u16* dstb = Kstg[(t - lo + 1) & 1];
#pragma unroll
      for (int j = 0; j < 2; j++) {
        int cc = (w * 2 + j) * 64 + lane;
        int row = cc >> 3, slot = cc & 7;
        async16(kbb + ((size_t)(t + 1) * 64 + row) * 64 + (slot ^ (row & 7)) * 8,
                (char*)dstb + (w * 2 + j) * 1024);
      }
    }
    const u16* Kb = Kstg[(t - lo) & 1];

    fx4 sA[4];
#pragma unroll
    for (int nt = 0; nt < 4; nt++) {
      int row = nt * 16 + ln;
      int s0_ = quad ^ (row & 7), s1_ = (quad + 4) ^ (row & 7);
      short8 kf0 = *(const short8*)(Kb + (row * 8 + s0_) * 8);
      short8 kf1 = *(const short8*)(Kb + (row * 8 + s1_) * 8);
      sA[nt] = mfma16(qf0, kf0, (fx4){0.f, 0.f, 0.f, 0.f});
      sA[nt] = mfma16(qf1, kf1, sA[nt]);
    }

    if (t == n - 1) {  // diagonal tile mask
#pragma unroll
      for (int nt = 0; nt < 4; nt++)
#pragma unroll
        for (int reg = 0; reg < 4; reg++) {
          int col = t * 64 + nt * 16 + ln;
          int rowg = q0 + w * 16 + quad * 4 + reg;
          if (col > rowg) sA[nt][reg] = -1e30f;
        }
    }

    // static max: p = 2^s (normalizer cancels); C-layout -> A-layout via LDS
#pragma unroll
    for (int nt = 0; nt < 4; nt++)
#pragma unroll
      for (int reg = 0; reg < 4; reg++)
        Ps[w][(quad * 4 + reg) * 72 + nt * 16 + ln] =
            f2bf(__builtin_amdgcn_exp2f(sA[nt][reg]));

    short8 pf0 = *(const short8*)(&Ps[w][ln * 72 + quad * 8]);
    short8 pf1 = *(const short8*)(&Ps[w][ln * 72 + 32 + quad * 8]);

    // row-sum of P via MFMA with ones-B
    fx4 lacc = mfma16(pf0, ones, (fx4){0.f, 0.f, 0.f, 0.f});
    lacc = mfma16(pf1, ones, lacc);
#pragma unroll
    for (int reg = 0; reg < 4; reg++) l_i[reg] += lacc[reg];

#pragma unroll
    for (int nt2 = 0; nt2 < 4; nt2++) {
      o[nt2] = mfma16(pf0, vf[nt2 * 2], o[nt2]);
      o[nt2] = mfma16(pf1, vf[nt2 * 2 + 1], o[nt2]);
    }
  }

  // write unnormalized partial + l; each wave owns its 16 rows (no merge barrier)
  float* dst = (z == 0) ? o0g : (po123 + (size_t)(z - 1) * 4 * 4096 * 64);
#pragma unroll
  for (int nt2 = 0; nt2 < 4; nt2++)
#pragma unroll
    for (int reg = 0; reg < 4; reg++) {
      int rowg = q0 + w * 16 + quad * 4 + reg;
      dst[((size_t)b * 4096 + rowg) * 64 + nt2 * 16 + ln] = o[nt2][reg];
    }
  if (ln == 0) {
#pragma unroll
    for (int reg = 0; reg < 4; reg++) {
      int rowg = q0 + w * 16 + quad * 4 + reg;
      mlb[((size_t)z * 4 + b) * 4096 + rowg] = l_i[reg];
    }
  }
}

// ---------------- merge the four split-K quarters: out = Σo_z / Σl_z
__global__ __launch_bounds__(256) void merge_kernel(float* __restrict__ out,
                                                    const float* __restrict__ po123,
                                                    const float* __restrict__ mlb) {
  int qt = blockIdx.x, b = blockIdx.y;
  int r = threadIdx.x >> 3;
  int c = (threadIdx.x & 7) * 8;
  size_t row = (size_t)b * 4096 + qt * 32 + r;
  float l = mlb[row];
#pragma unroll
  for (int z = 1; z < 4; z++) l += mlb[(size_t)z * 4 * 4096 + row];
  float inv = 1.0f / l;
  float* op = out + row * 64 + c;
  fx4 u0 = *(fx4*)op, u1 = *(fx4*)(op + 4);
#pragma unroll
  for (int z = 1; z < 4; z++) {
    const float* pp = po123 + (size_t)(z - 1) * 4 * 4096 * 64 + row * 64 + c;
    fx4 v0 = *(const fx4*)pp, v1 = *(const fx4*)(pp + 4);
#pragma unroll
    for (int j = 0; j < 4; j++) { u0[j] += v0[j]; u1[j] += v1[j]; }
  }
#pragma unroll
  for (int j = 0; j < 4; j++) { u0[j] *= inv; u1[j] *= inv; }
  *(fx4*)op = u0;
  *(fx4*)(op + 4) = u1;
}

extern "C" void kernel_launch(void* const* d_in, const int* in_sizes, int n_in,
                              void* d_out, int out_size, void* d_ws, size_t ws_size,
                              hipStream_t stream) {
  const float* x  = (const float*)d_in[0];
  const float* Wq = (const float*)d_in[1];
  const float* Wk = (const float*)d_in[2];
  const float* Wv = (const float*)d_in[3];

  u16* qbw = (u16*)d_ws;                          // [16384][64] bf16, 2MB
  u16* kbw = qbw + (size_t)TOKENS * 64;           // 2MB
  u16* vtw = kbw + (size_t)TOKENS * 64;           // 2MB
  u16* wfr = vtw + (size_t)TOKENS * 64;           // 288KB
  float* po123 = (float*)(wfr + (size_t)3 * KSTEPS * 256 * 8);  // 3x [4][4096][64] fp32, 12MB
  float* mlb = po123 + (size_t)3 * 4 * 4096 * 64; // [4][4][4096] float, 256KB

  prep_w_kernel<<<72, 256, 0, stream>>>(Wq, Wk, Wv, wfr);
  proj_kernel<<<TOKENS / 16, 256, 0, stream>>>(x, wfr, qbw, kbw, vtw);
  attn_kernel<<<dim3(64, 4, 4), 256, 0, stream>>>(qbw, kbw, vtw,
                                                  (float*)d_out, po123, mlb);
  merge_kernel<<<dim3(128, 4), 256, 0, stream>>>((float*)d_out, po123, mlb);
}

// Round 10
// 139.967 us; speedup vs baseline: 1.6627x; 1.3240x over previous
//
#include <hip/hip_runtime.h>
#include <stdint.h>

#define KSTEPS 24              // 768 / 32
#define TOKENS 16384           // B*S

typedef short short8 __attribute__((ext_vector_type(8)));
typedef float fx4 __attribute__((ext_vector_type(4)));
typedef unsigned short u16;
typedef u16 u16x4 __attribute__((ext_vector_type(4)));

static __device__ __forceinline__ u16 f2bf(float f) {
  union { float f; unsigned u; } v; v.f = f;
  return (u16)((v.u + 0x7fffu + ((v.u >> 16) & 1u)) >> 16);
}

static __device__ __forceinline__ fx4 mfma16(short8 a, short8 b, fx4 c) {
  return __builtin_amdgcn_mfma_f32_16x16x32_bf16(a, b, c, 0, 0, 0);
}

// async global->LDS, 16B/lane; lds dest = wave-uniform base + lane*16
static __device__ __forceinline__ void async16(const void* g, void* l) {
  __builtin_amdgcn_global_load_lds(
      (const __attribute__((address_space(1))) void*)g,
      (__attribute__((address_space(3))) void*)(unsigned int)(uintptr_t)l,
      16, 0, 0);
}

// ---------------- prep: W[768][64] fp32 (q,k,v) -> bf16 pre-fragmented B-operand layout
__global__ void prep_w_kernel(const float* __restrict__ Wq, const float* __restrict__ Wk,
                              const float* __restrict__ Wv, u16* __restrict__ wfrag) {
  int idx  = blockIdx.x * 256 + threadIdx.x;   // 72*256 = 18432 = 3*24*4*64
  int lane = idx & 63;
  int fid  = idx >> 6;
  int nt   = fid & 3;
  int ks   = (fid >> 2) % KSTEPS;
  int mat  = fid / (KSTEPS * 4);
  const float* W = (mat == 0) ? Wq : (mat == 1) ? Wk : Wv;
  int n  = nt * 16 + (lane & 15);
  int k0 = ks * 32 + (lane >> 4) * 8;
  short8 out;
#pragma unroll
  for (int j = 0; j < 8; j++) out[j] = (short)f2bf(W[(size_t)(k0 + j) * 64 + n]);
  *(short8*)(wfrag + (size_t)idx * 8) = out;
}

// ---------------- projection GEMM (r3/r5 LDS-staged version — best measured)
// 32 tok/block, 256 thr; W+x staged via global_load_lds, double-buffered.
__global__ __launch_bounds__(256) void proj_kernel(const float* __restrict__ x,
                                                   const u16* __restrict__ wfrag,
                                                   u16* __restrict__ qb,
                                                   u16* __restrict__ kb,
                                                   u16* __restrict__ vT) {
  __shared__ float xs[2][32 * 32];    // [dbuf][tok][32 floats] chunk-swizzled
  __shared__ u16  Ws[2][12 * 512];    // [dbuf][f=(m*4+nt)][lane][8]

  int w = threadIdx.x >> 6, lane = threadIdx.x & 63;
  int ln = lane & 15, quad = lane >> 4;
  int rw = w >> 1, cs = w & 1;
  int s0 = blockIdx.x * 32;

  fx4 acc[6];
#pragma unroll
  for (int j = 0; j < 6; j++) acc[j] = (fx4){0.f, 0.f, 0.f, 0.f};

  int srow  = w * 8 + (lane >> 3);
  int slot  = lane & 7;
  int chunk = slot ^ (srow & 7);
  const float* xsrc = x + (size_t)(s0 + srow) * 768 + chunk * 4;

#pragma unroll
  for (int m = 0; m < 3; m++)
    async16(wfrag + ((size_t)(m * KSTEPS + 0) * 256 + w * 64 + lane) * 8,
            (char*)Ws[0] + m * 4096 + w * 1024 + lane * 16);
  async16(xsrc, (char*)xs[0] + w * 1024 + lane * 16);

  int r = rw * 16 + ln;
  for (int ks = 0; ks < KSTEPS; ks++) {
    __syncthreads();
    if (ks < KSTEPS - 1) {
      int buf = (ks + 1) & 1;
#pragma unroll
      for (int m = 0; m < 3; m++)
        async16(wfrag + ((size_t)(m * KSTEPS + ks + 1) * 256 + w * 64 + lane) * 8,
                (char*)Ws[buf] + m * 4096 + w * 1024 + lane * 16);
      async16(xsrc + (ks + 1) * 32, (char*)xs[buf] + w * 1024 + lane * 16);
    }
    const float* xb = xs[ks & 1];
    const u16*  wb = Ws[ks & 1];
    int sl0 = (2 * quad)     ^ (r & 7);
    int sl1 = (2 * quad + 1) ^ (r & 7);
    fx4 xa = *(const fx4*)(xb + r * 32 + sl0 * 4);
    fx4 xv = *(const fx4*)(xb + r * 32 + sl1 * 4);
    short8 af;
#pragma unroll
    for (int j = 0; j < 4; j++) { af[j] = (short)f2bf(xa[j]); af[4 + j] = (short)f2bf(xv[j]); }
#pragma unroll
    for (int j = 0; j < 6; j++) {
      short8 bf = *(const short8*)(wb + (cs * 6 + j) * 512 + lane * 8);
      acc[j] = mfma16(af, bf, acc[j]);
    }
  }

  int tok0 = s0 + rw * 16 + quad * 4;
#pragma unroll
  for (int j = 0; j < 6; j++) {
    int f = cs * 6 + j;
    int d = (f & 3) * 16 + ln;
    if (f < 4) {
      // Q pre-scaled by 0.125 * log2(e): scores land in exp2 domain
#pragma unroll
      for (int reg = 0; reg < 4; reg++)
        qb[(size_t)(tok0 + reg) * 64 + d] = f2bf(acc[j][reg] * 0.180336887f);
    } else if (f < 8) {
#pragma unroll
      for (int reg = 0; reg < 4; reg++)
        kb[(size_t)(tok0 + reg) * 64 + d] = f2bf(acc[j][reg]);
    } else {
      int b = tok0 >> 12, s = tok0 & 4095;
      u16x4 vp;
#pragma unroll
      for (int reg = 0; reg < 4; reg++) vp[reg] = f2bf(acc[j][reg]);
      *(u16x4*)(vT + ((size_t)b * 64 + d) * 4096 + s) = vp;
    }
  }
}

// ---------------- flash attention v6: BM=64, K AND V both DMA-staged (dbuf).
// Split-K 4-way across blocks; static-max softmax (p = 2^s, partials additive).
// Per-round chain is pure LDS+VALU+MFMA: no global-latency element.
__global__ __launch_bounds__(256) void attn_kernel(const u16* __restrict__ qb,
                                                   const u16* __restrict__ kb,
                                                   const u16* __restrict__ vT,
                                                   float* __restrict__ o0g,
                                                   float* __restrict__ po123,
                                                   float* __restrict__ mlb) {
  __shared__ u16 Kstg[2][4096];       // [buf][64 keys x 64 d]   16KB
  __shared__ u16 Vstg[2][4096];       // [buf][64 d x 64 keys]   16KB  (V^T layout)
  __shared__ u16 Ps[4][16 * 72];      // per-wave P round-trip, padded rows

  int w = threadIdx.x >> 6, lane = threadIdx.x & 63;
  int ln = lane & 15, quad = lane >> 4;
  int band = 63 - blockIdx.x;         // 64-row band, big workloads first
  int b = blockIdx.y, z = blockIdx.z; // batch, split-K quarter
  int q0 = band * 64;

  const u16* qbb = qb + (size_t)b * 4096 * 64;
  const u16* kbb = kb + (size_t)b * 4096 * 64;
  const u16* vtb = vT + (size_t)b * 64 * 4096;

  short8 qf0 = *(const short8*)(qbb + (size_t)(q0 + w * 16 + ln) * 64 + quad * 8);
  short8 qf1 = *(const short8*)(qbb + (size_t)(q0 + w * 16 + ln) * 64 + 32 + quad * 8);

  short8 ones;
#pragma unroll
  for (int j = 0; j < 8; j++) ones[j] = (short)0x3F80;   // bf16 1.0

  fx4 o[4];
#pragma unroll
  for (int nt2 = 0; nt2 < 4; nt2++) o[nt2] = (fx4){0.f, 0.f, 0.f, 0.f};
  float l_i[4] = {0.f, 0.f, 0.f, 0.f};

  int n = band + 1;                   // 64-key tiles this band needs
  int c = (n + 3) >> 2;               // tiles per split-K quarter
  int lo = z * c; if (lo > n) lo = n;
  int hi = lo + c; if (hi > n) hi = n;

  // staging: each tile is 64 rows x 128B; 512 chunks of 16B; 2 chunks/thread each
  // K row = key (kb[tok][64] contiguous); V row = d (vT[d][4096] contiguous)
  if (lo < hi) {
#pragma unroll
    for (int j = 0; j < 2; j++) {
      int cc = (w * 2 + j) * 64 + lane;
      int row = cc >> 3, slot = cc & 7, sw = (slot ^ (row & 7)) * 8;
      async16(kbb + ((size_t)lo * 64 + row) * 64 + sw, (char*)Kstg[0] + (w * 2 + j) * 1024);
      async16(vtb + (size_t)row * 4096 + lo * 64 + sw, (char*)Vstg[0] + (w * 2 + j) * 1024);
    }
  }

  for (int t = lo; t < hi; t++) {
    __syncthreads();                  // publishes buf (t-lo)&1
    if (t + 1 < hi) {                 // prefetch next K+V tiles into other buf
      int nb = (t - lo + 1) & 1;
#pragma unroll
      for (int j = 0; j < 2; j++) {
        int cc = (w * 2 + j) * 64 + lane;
        int row = cc >> 3, slot = cc & 7, sw = (slot ^ (row & 7)) * 8;
        async16(kbb + ((size_t)(t + 1) * 64 + row) * 64 + sw,
                (char*)Kstg[nb] + (w * 2 + j) * 1024);
        async16(vtb + (size_t)row * 4096 + (t + 1) * 64 + sw,
                (char*)Vstg[nb] + (w * 2 + j) * 1024);
      }
    }
    const u16* Kb = Kstg[(t - lo) & 1];
    const u16* Vb = Vstg[(t - lo) & 1];

    fx4 sA[4];
#pragma unroll
    for (int nt = 0; nt < 4; nt++) {
      int row = nt * 16 + ln;
      int s0_ = quad ^ (row & 7), s1_ = (quad + 4) ^ (row & 7);
      short8 kf0 = *(const short8*)(Kb + (row * 8 + s0_) * 8);
      short8 kf1 = *(const short8*)(Kb + (row * 8 + s1_) * 8);
      sA[nt] = mfma16(qf0, kf0, (fx4){0.f, 0.f, 0.f, 0.f});
      sA[nt] = mfma16(qf1, kf1, sA[nt]);
    }

    if (t == n - 1) {  // diagonal tile mask
#pragma unroll
      for (int nt = 0; nt < 4; nt++)
#pragma unroll
        for (int reg = 0; reg < 4; reg++) {
          int col = t * 64 + nt * 16 + ln;
          int rowg = q0 + w * 16 + quad * 4 + reg;
          if (col > rowg) sA[nt][reg] = -1e30f;
        }
    }

    // static max: p = 2^s (normalizer cancels); C-layout -> A-layout via LDS
#pragma unroll
    for (int nt = 0; nt < 4; nt++)
#pragma unroll
      for (int reg = 0; reg < 4; reg++)
        Ps[w][(quad * 4 + reg) * 72 + nt * 16 + ln] =
            f2bf(__builtin_amdgcn_exp2f(sA[nt][reg]));

    short8 pf0 = *(const short8*)(&Ps[w][ln * 72 + quad * 8]);
    short8 pf1 = *(const short8*)(&Ps[w][ln * 72 + 32 + quad * 8]);

    // row-sum of P via MFMA with ones-B
    fx4 lacc = mfma16(pf0, ones, (fx4){0.f, 0.f, 0.f, 0.f});
    lacc = mfma16(pf1, ones, lacc);
#pragma unroll
    for (int reg = 0; reg < 4; reg++) l_i[reg] += lacc[reg];

    // PV: V B-frag from LDS V^T tile: row = d (nt2*16+ln), chunks quad / quad+4
#pragma unroll
    for (int nt2 = 0; nt2 < 4; nt2++) {
      int row = nt2 * 16 + ln;
      int s0_ = quad ^ (row & 7), s1_ = (quad + 4) ^ (row & 7);
      short8 vf0 = *(const short8*)(Vb + (row * 8 + s0_) * 8);
      short8 vf1 = *(const short8*)(Vb + (row * 8 + s1_) * 8);
      o[nt2] = mfma16(pf0, vf0, o[nt2]);
      o[nt2] = mfma16(pf1, vf1, o[nt2]);
    }
  }

  // write unnormalized partial + l; each wave owns its 16 rows (no merge barrier)
  float* dst = (z == 0) ? o0g : (po123 + (size_t)(z - 1) * 4 * 4096 * 64);
#pragma unroll
  for (int nt2 = 0; nt2 < 4; nt2++)
#pragma unroll
    for (int reg = 0; reg < 4; reg++) {
      int rowg = q0 + w * 16 + quad * 4 + reg;
      dst[((size_t)b * 4096 + rowg) * 64 + nt2 * 16 + ln] = o[nt2][reg];
    }
  if (ln == 0) {
#pragma unroll
    for (int reg = 0; reg < 4; reg++) {
      int rowg = q0 + w * 16 + quad * 4 + reg;
      mlb[((size_t)z * 4 + b) * 4096 + rowg] = l_i[reg];
    }
  }
}

// ---------------- merge the four split-K quarters: out = Σo_z / Σl_z
__global__ __launch_bounds__(256) void merge_kernel(float* __restrict__ out,
                                                    const float* __restrict__ po123,
                                                    const float* __restrict__ mlb) {
  int qt = blockIdx.x, b = blockIdx.y;
  int r = threadIdx.x >> 3;
  int c = (threadIdx.x & 7) * 8;
  size_t row = (size_t)b * 4096 + qt * 32 + r;
  float l = mlb[row];
#pragma unroll
  for (int z = 1; z < 4; z++) l += mlb[(size_t)z * 4 * 4096 + row];
  float inv = 1.0f / l;
  float* op = out + row * 64 + c;
  fx4 u0 = *(fx4*)op, u1 = *(fx4*)(op + 4);
#pragma unroll
  for (int z = 1; z < 4; z++) {
    const float* pp = po123 + (size_t)(z - 1) * 4 * 4096 * 64 + row * 64 + c;
    fx4 v0 = *(const fx4*)pp, v1 = *(const fx4*)(pp + 4);
#pragma unroll
    for (int j = 0; j < 4; j++) { u0[j] += v0[j]; u1[j] += v1[j]; }
  }
#pragma unroll
  for (int j = 0; j < 4; j++) { u0[j] *= inv; u1[j] *= inv; }
  *(fx4*)op = u0;
  *(fx4*)(op + 4) = u1;
}

extern "C" void kernel_launch(void* const* d_in, const int* in_sizes, int n_in,
                              void* d_out, int out_size, void* d_ws, size_t ws_size,
                              hipStream_t stream) {
  const float* x  = (const float*)d_in[0];
  const float* Wq = (const float*)d_in[1];
  const float* Wk = (const float*)d_in[2];
  const float* Wv = (const float*)d_in[3];

  u16* qbw = (u16*)d_ws;                          // [16384][64] bf16, 2MB
  u16* kbw = qbw + (size_t)TOKENS * 64;           // 2MB
  u16* vtw = kbw + (size_t)TOKENS * 64;           // 2MB
  u16* wfr = vtw + (size_t)TOKENS * 64;           // 288KB
  float* po123 = (float*)(wfr + (size_t)3 * KSTEPS * 256 * 8);  // 3x [4][4096][64] fp32
  float* mlb = po123 + (size_t)3 * 4 * 4096 * 64; // [4][4][4096] float

  prep_w_kernel<<<72, 256, 0, stream>>>(Wq, Wk, Wv, wfr);
  proj_kernel<<<TOKENS / 32, 256, 0, stream>>>(x, wfr, qbw, kbw, vtw);
  attn_kernel<<<dim3(64, 4, 4), 256, 0, stream>>>(qbw, kbw, vtw,
                                                  (float*)d_out, po123, mlb);
  merge_kernel<<<dim3(128, 4), 256, 0, stream>>>((float*)d_out, po123, mlb);
}